// Round 1
// baseline (2157.579 us; speedup 1.0000x reference)
//
#include <hip/hip_runtime.h>

// PairMixing: y_L[n,k,f] = sum_{triples (l1,l2,L)} (rbf[n,:]·W_t[f,:]) *
//                          sum_{i,j} cg_t[i,j,k] * x1_{l1}[n,i,f] * x2_{l2}[n,j,f]
// N=60000, F=128, B=32, 15 triples.
//
// v2 structure: one thread per (n,f) stream, 2 n's per thread (single pass).
// block = 256 = 128 f-lanes x 2 n-halves, NB=4 pairs/block -> grid 15000.
//
// Phase 1 (coeff) is b-chunk-outer / triple-inner: per chunk only 16 wave-uniform
// rbf values are live (one s_load batch), reused by all 15 triples -> kills the
// per-triple rbf reload storm of the previous version. W rows stream as float4
// (L2-resident, 245 KB total).
// Phase 2 unchanged math; cf[15][2] + halved x/y arrays keep peak VGPR ~115 so
// __launch_bounds__(256,4) gives 4 waves/SIMD (prev: measured ~2.6).

#define NPAIR 60000
#define NB    4
#define Y1OFF (NPAIR * 128)        // 7,680,000
#define Y2OFF (NPAIR * 128 * 4)    // 30,720,000

template<int D1, int D2, int DK>
__device__ __forceinline__ void triple_acc(
    const float* __restrict__ cg,
    const float (&a)[D1][2], const float (&b)[D2][2],
    float cf0, float cf1, float (&y)[DK][2])
{
    float tp[DK][2];
#pragma unroll
    for (int k = 0; k < DK; ++k) { tp[k][0] = 0.f; tp[k][1] = 0.f; }
#pragma unroll
    for (int i = 0; i < D1; ++i) {
#pragma unroll
        for (int j = 0; j < D2; ++j) {
#pragma unroll
            for (int nn = 0; nn < 2; ++nn) {
                const float prod = a[i][nn] * b[j][nn];
#pragma unroll
                for (int k = 0; k < DK; ++k) {
                    // cg[...] is a uniform address -> scalar load; SGPR operand in fma
                    tp[k][nn] = fmaf(cg[(i * D2 + j) * DK + k], prod, tp[k][nn]);
                }
            }
        }
    }
#pragma unroll
    for (int k = 0; k < DK; ++k) {
        y[k][0] = fmaf(cf0, tp[k][0], y[k][0]);
        y[k][1] = fmaf(cf1, tp[k][1], y[k][1]);
    }
}

__global__ __launch_bounds__(256, 4) void pair_mixing_kernel(
    const float* __restrict__ x1_0, const float* __restrict__ x1_1, const float* __restrict__ x1_2,
    const float* __restrict__ x2_0, const float* __restrict__ x2_1, const float* __restrict__ x2_2,
    const float* __restrict__ rbf,
    const float* __restrict__ cg0,  const float* __restrict__ cg1,  const float* __restrict__ cg2,
    const float* __restrict__ cg3,  const float* __restrict__ cg4,  const float* __restrict__ cg5,
    const float* __restrict__ cg6,  const float* __restrict__ cg7,  const float* __restrict__ cg8,
    const float* __restrict__ cg9,  const float* __restrict__ cg10, const float* __restrict__ cg11,
    const float* __restrict__ cg12, const float* __restrict__ cg13, const float* __restrict__ cg14,
    const float* __restrict__ W0,  const float* __restrict__ W1,  const float* __restrict__ W2,
    const float* __restrict__ W3,  const float* __restrict__ W4,  const float* __restrict__ W5,
    const float* __restrict__ W6,  const float* __restrict__ W7,  const float* __restrict__ W8,
    const float* __restrict__ W9,  const float* __restrict__ W10, const float* __restrict__ W11,
    const float* __restrict__ W12, const float* __restrict__ W13, const float* __restrict__ W14,
    float* __restrict__ out)
{
    const int tid = threadIdx.x;
    const int f   = tid & 127;
    const int sub = tid >> 7;                  // 0 or 1: which 2-n half
    const int nb  = blockIdx.x * NB + sub * 2; // first n for this thread
    // uniform per wave (waves 0,1 -> sub 0; waves 2,3 -> sub 1)
    const int nbu = __builtin_amdgcn_readfirstlane(nb);
    const float* rbfp = rbf + ((size_t)nbu << 5);   // uniform base -> scalar-load path

    // ---- x loads first: VMEM latency overlaps the whole coeff phase ----
    float a0[1][2], a1[3][2], a2[5][2];
    float c0[1][2], c1[3][2], c2[5][2];
#pragma unroll
    for (int nn = 0; nn < 2; ++nn) {
        const int n = nb + nn;
        a0[0][nn] = x1_0[n * 128 + f];
#pragma unroll
        for (int i = 0; i < 3; ++i) a1[i][nn] = x1_1[(n * 3 + i) * 128 + f];
#pragma unroll
        for (int i = 0; i < 5; ++i) a2[i][nn] = x1_2[(n * 5 + i) * 128 + f];
        c0[0][nn] = x2_0[n * 128 + f];
#pragma unroll
        for (int j = 0; j < 3; ++j) c1[j][nn] = x2_1[(n * 3 + j) * 128 + f];
#pragma unroll
        for (int j = 0; j < 5; ++j) c2[j][nn] = x2_2[(n * 5 + j) * 128 + f];
    }

    // ---- phase 1: coeff[t][nn] = rbf[n+nn,:] . W_t[f,:] ----
    // chunk-outer (8 b's live at a time), triple-inner.
    const float* Wt[15] = {W0, W1, W2, W3, W4, W5, W6, W7,
                           W8, W9, W10, W11, W12, W13, W14};
    float cf[15][2];
#pragma unroll
    for (int t = 0; t < 15; ++t) { cf[t][0] = 0.f; cf[t][1] = 0.f; }

#pragma unroll
    for (int ch = 0; ch < 4; ++ch) {
        // 16 wave-uniform rbf values for this chunk (2 n's x 8 b's) -> SGPRs
        float rb0[8], rb1[8];
#pragma unroll
        for (int b = 0; b < 8; ++b) {
            rb0[b] = rbfp[ch * 8 + b];
            rb1[b] = rbfp[32 + ch * 8 + b];
        }
#pragma unroll
        for (int t = 0; t < 15; ++t) {
            const float4* wp = (const float4*)(Wt[t] + ((size_t)f << 5) + ch * 8);
            const float4 w0 = wp[0];
            const float4 w1 = wp[1];
            const float wv[8] = {w0.x, w0.y, w0.z, w0.w, w1.x, w1.y, w1.z, w1.w};
#pragma unroll
            for (int b = 0; b < 8; ++b) {
                cf[t][0] = fmaf(rb0[b], wv[b], cf[t][0]);
                cf[t][1] = fmaf(rb1[b], wv[b], cf[t][1]);
            }
        }
    }

    // ---- phase 2: tensor products for the 2 n's ----
    float y0v[1][2], y1v[3][2], y2v[5][2];
#pragma unroll
    for (int k = 0; k < 1; ++k) { y0v[k][0] = 0.f; y0v[k][1] = 0.f; }
#pragma unroll
    for (int k = 0; k < 3; ++k) { y1v[k][0] = 0.f; y1v[k][1] = 0.f; }
#pragma unroll
    for (int k = 0; k < 5; ++k) { y2v[k][0] = 0.f; y2v[k][1] = 0.f; }

    triple_acc<1,1,1>(cg0,  a0, c0, cf[0][0],  cf[0][1],  y0v);  // (0,0,0)
    triple_acc<1,3,3>(cg1,  a0, c1, cf[1][0],  cf[1][1],  y1v);  // (0,1,1)
    triple_acc<1,5,5>(cg2,  a0, c2, cf[2][0],  cf[2][1],  y2v);  // (0,2,2)
    triple_acc<3,1,3>(cg3,  a1, c0, cf[3][0],  cf[3][1],  y1v);  // (1,0,1)
    triple_acc<3,3,1>(cg4,  a1, c1, cf[4][0],  cf[4][1],  y0v);  // (1,1,0)
    triple_acc<3,3,3>(cg5,  a1, c1, cf[5][0],  cf[5][1],  y1v);  // (1,1,1)
    triple_acc<3,3,5>(cg6,  a1, c1, cf[6][0],  cf[6][1],  y2v);  // (1,1,2)
    triple_acc<3,5,3>(cg7,  a1, c2, cf[7][0],  cf[7][1],  y1v);  // (1,2,1)
    triple_acc<3,5,5>(cg8,  a1, c2, cf[8][0],  cf[8][1],  y2v);  // (1,2,2)
    triple_acc<5,1,5>(cg9,  a2, c0, cf[9][0],  cf[9][1],  y2v);  // (2,0,2)
    triple_acc<5,3,3>(cg10, a2, c1, cf[10][0], cf[10][1], y1v);  // (2,1,1)
    triple_acc<5,3,5>(cg11, a2, c1, cf[11][0], cf[11][1], y2v);  // (2,1,2)
    triple_acc<5,5,1>(cg12, a2, c2, cf[12][0], cf[12][1], y0v);  // (2,2,0)
    triple_acc<5,5,3>(cg13, a2, c2, cf[13][0], cf[13][1], y1v);  // (2,2,1)
    triple_acc<5,5,5>(cg14, a2, c2, cf[14][0], cf[14][1], y2v);  // (2,2,2)

    // ---- stores ----
#pragma unroll
    for (int nn = 0; nn < 2; ++nn) {
        const int n = nb + nn;
        out[n * 128 + f] = y0v[0][nn];
#pragma unroll
        for (int k = 0; k < 3; ++k)
            out[Y1OFF + (n * 3 + k) * 128 + f] = y1v[k][nn];
#pragma unroll
        for (int k = 0; k < 5; ++k)
            out[Y2OFF + (n * 5 + k) * 128 + f] = y2v[k][nn];
    }
}

extern "C" void kernel_launch(void* const* d_in, const int* in_sizes, int n_in,
                              void* d_out, int out_size, void* d_ws, size_t ws_size,
                              hipStream_t stream) {
    const float* x1_0 = (const float*)d_in[0];
    const float* x1_1 = (const float*)d_in[1];
    const float* x1_2 = (const float*)d_in[2];
    const float* x2_0 = (const float*)d_in[3];
    const float* x2_1 = (const float*)d_in[4];
    const float* x2_2 = (const float*)d_in[5];
    const float* rbf  = (const float*)d_in[6];
    // setup_inputs order: per triple, cg then W, interleaved
    const float* cg[15];
    const float* W[15];
    for (int t = 0; t < 15; ++t) {
        cg[t] = (const float*)d_in[7 + 2 * t];
        W[t]  = (const float*)d_in[8 + 2 * t];
    }
    float* out = (float*)d_out;

    dim3 grid(NPAIR / NB);   // 15000
    dim3 block(256);
    pair_mixing_kernel<<<grid, block, 0, stream>>>(
        x1_0, x1_1, x1_2, x2_0, x2_1, x2_2, rbf,
        cg[0], cg[1], cg[2], cg[3], cg[4], cg[5], cg[6], cg[7],
        cg[8], cg[9], cg[10], cg[11], cg[12], cg[13], cg[14],
        W[0], W[1], W[2], W[3], W[4], W[5], W[6], W[7],
        W[8], W[9], W[10], W[11], W[12], W[13], W[14],
        out);
}

// Round 2
// 1123.537 us; speedup vs baseline: 1.9203x; 1.9203x over previous
//
#include <hip/hip_runtime.h>

// PairMixing: y_L[n,k,f] = sum_{triples (l1,l2,L)} (rbf[n,:]·W_t[f,:]) *
//                          sum_{i,j} cg_t[i,j,k] * x1_{l1}[n,i,f] * x2_{l2}[n,j,f]
// N=60000, F=128, B=32, 15 triples.
//
// v3: the W reads were the bottleneck (thread f reads W_t[f,:] -> 128-B lane
// stride -> ~64 L1 lines per float4 wave-instr; ~375us of L1 transactions in v1,
// ~750us in v2). Fix: prologue kernel transposes W into workspace as
// WT4[t][q][f][4] (245 KB) so the main kernel's W fragment loads are fully
// coalesced float4s. Main kernel restores 4 n/thread (NB=8) to amortize W loads
// and keeps v2's b-chunk-outer coeff loop (bounded rbf s_load live-set) +
// v1's two-pass phase 2.

#define NPAIR 60000
#define NB    8
#define Y1OFF (NPAIR * 128)        // 7,680,000
#define Y2OFF (NPAIR * 128 * 4)    // 30,720,000
#define WT_BYTES (15 * 128 * 32 * 4)   // 245,760

struct WPtrs { const float* w[15]; };

// WT4 linear float4 index: (t*8 + q)*128 + f   <=>  WT4[t][q][f] = W_t[f][4q:4q+4]
__global__ void transpose_W_kernel(WPtrs P, float* __restrict__ WT) {
    const int t  = blockIdx.y;                      // uniform -> s_load of pointer
    const int id = blockIdx.x * 256 + threadIdx.x;  // 0..1023
    const int f  = id >> 3;
    const int q  = id & 7;
    const float4 v = ((const float4*)(P.w[t] + f * 32))[q];   // coalesced read
    ((float4*)WT)[(t * 8 + q) * 128 + f] = v;                 // small scattered write (245 KB total)
}

template<int D1, int D2, int DK>
__device__ __forceinline__ void triple_acc(
    const float* __restrict__ cg,
    const float (&a)[D1][2], const float (&b)[D2][2],
    float cf0, float cf1, float (&y)[DK][2])
{
    float tp[DK][2];
#pragma unroll
    for (int k = 0; k < DK; ++k) { tp[k][0] = 0.f; tp[k][1] = 0.f; }
#pragma unroll
    for (int i = 0; i < D1; ++i) {
#pragma unroll
        for (int j = 0; j < D2; ++j) {
#pragma unroll
            for (int nn = 0; nn < 2; ++nn) {
                const float prod = a[i][nn] * b[j][nn];
#pragma unroll
                for (int k = 0; k < DK; ++k) {
                    // cg[...] is a uniform address -> scalar load; SGPR operand in fma
                    tp[k][nn] = fmaf(cg[(i * D2 + j) * DK + k], prod, tp[k][nn]);
                }
            }
        }
    }
#pragma unroll
    for (int k = 0; k < DK; ++k) {
        y[k][0] = fmaf(cf0, tp[k][0], y[k][0]);
        y[k][1] = fmaf(cf1, tp[k][1], y[k][1]);
    }
}

template<bool USE_WT>
__global__ __launch_bounds__(256, 4) void pair_mixing_kernel(
    const float* __restrict__ x1_0, const float* __restrict__ x1_1, const float* __restrict__ x1_2,
    const float* __restrict__ x2_0, const float* __restrict__ x2_1, const float* __restrict__ x2_2,
    const float* __restrict__ rbf,
    const float* __restrict__ cg0,  const float* __restrict__ cg1,  const float* __restrict__ cg2,
    const float* __restrict__ cg3,  const float* __restrict__ cg4,  const float* __restrict__ cg5,
    const float* __restrict__ cg6,  const float* __restrict__ cg7,  const float* __restrict__ cg8,
    const float* __restrict__ cg9,  const float* __restrict__ cg10, const float* __restrict__ cg11,
    const float* __restrict__ cg12, const float* __restrict__ cg13, const float* __restrict__ cg14,
    const float* __restrict__ W0,  const float* __restrict__ W1,  const float* __restrict__ W2,
    const float* __restrict__ W3,  const float* __restrict__ W4,  const float* __restrict__ W5,
    const float* __restrict__ W6,  const float* __restrict__ W7,  const float* __restrict__ W8,
    const float* __restrict__ W9,  const float* __restrict__ W10, const float* __restrict__ W11,
    const float* __restrict__ W12, const float* __restrict__ W13, const float* __restrict__ W14,
    const float* __restrict__ WT,
    float* __restrict__ out)
{
    const int tid = threadIdx.x;
    const int f   = tid & 127;
    const int sub = tid >> 7;                     // 0 or 1: which 4-n half
    const int nbt = blockIdx.x * NB + sub * 4;    // first n for this thread
    // uniform per wave (waves 0,1 -> sub 0; waves 2,3 -> sub 1)
    const int nbu = __builtin_amdgcn_readfirstlane(nbt);
    const float* rbfp = rbf + ((size_t)nbu << 5); // uniform base -> scalar-load path

    // ---- phase 1: coeff[t][nn] = rbf[n+nn,:] . W_t[f,:] ----
    // b-chunk-outer (16 uniform rbf scalars live), triple-inner, coalesced W.
    const float* Wt[15] = {W0, W1, W2, W3, W4, W5, W6, W7,
                           W8, W9, W10, W11, W12, W13, W14};
    float cf[15][4];
#pragma unroll
    for (int t = 0; t < 15; ++t)
#pragma unroll
        for (int nn = 0; nn < 4; ++nn) cf[t][nn] = 0.f;

#pragma unroll
    for (int q = 0; q < 8; ++q) {
        float rb[4][4];
#pragma unroll
        for (int nn = 0; nn < 4; ++nn)
#pragma unroll
            for (int r = 0; r < 4; ++r)
                rb[nn][r] = rbfp[nn * 32 + q * 4 + r];
#pragma unroll
        for (int t = 0; t < 15; ++t) {
            float4 w;
            if (USE_WT) {
                // coalesced: consecutive lanes f -> consecutive float4s
                w = ((const float4*)WT)[(t * 8 + q) * 128 + f];
            } else {
                // fallback: strided direct read (v1 behavior)
                w = ((const float4*)(Wt[t] + ((size_t)f << 5)))[q];
            }
            const float wv[4] = {w.x, w.y, w.z, w.w};
#pragma unroll
            for (int r = 0; r < 4; ++r)
#pragma unroll
                for (int nn = 0; nn < 4; ++nn)
                    cf[t][nn] = fmaf(rb[nn][r], wv[r], cf[t][nn]);
        }
    }

    // ---- phase 2: tensor products, two passes of 2 n's each ----
#pragma unroll
    for (int pass = 0; pass < 2; ++pass) {
        const int nb = nbt + pass * 2;

        float a0[1][2], a1[3][2], a2[5][2];
        float c0[1][2], c1[3][2], c2[5][2];
#pragma unroll
        for (int nn = 0; nn < 2; ++nn) {
            const int n = nb + nn;
            a0[0][nn] = x1_0[n * 128 + f];
#pragma unroll
            for (int i = 0; i < 3; ++i) a1[i][nn] = x1_1[(n * 3 + i) * 128 + f];
#pragma unroll
            for (int i = 0; i < 5; ++i) a2[i][nn] = x1_2[(n * 5 + i) * 128 + f];
            c0[0][nn] = x2_0[n * 128 + f];
#pragma unroll
            for (int j = 0; j < 3; ++j) c1[j][nn] = x2_1[(n * 3 + j) * 128 + f];
#pragma unroll
            for (int j = 0; j < 5; ++j) c2[j][nn] = x2_2[(n * 5 + j) * 128 + f];
        }

        float y0v[1][2], y1v[3][2], y2v[5][2];
#pragma unroll
        for (int k = 0; k < 1; ++k) { y0v[k][0] = 0.f; y0v[k][1] = 0.f; }
#pragma unroll
        for (int k = 0; k < 3; ++k) { y1v[k][0] = 0.f; y1v[k][1] = 0.f; }
#pragma unroll
        for (int k = 0; k < 5; ++k) { y2v[k][0] = 0.f; y2v[k][1] = 0.f; }

        const int p0 = 2 * pass, p1 = 2 * pass + 1;
        triple_acc<1,1,1>(cg0,  a0, c0, cf[0][p0],  cf[0][p1],  y0v);  // (0,0,0)
        triple_acc<1,3,3>(cg1,  a0, c1, cf[1][p0],  cf[1][p1],  y1v);  // (0,1,1)
        triple_acc<1,5,5>(cg2,  a0, c2, cf[2][p0],  cf[2][p1],  y2v);  // (0,2,2)
        triple_acc<3,1,3>(cg3,  a1, c0, cf[3][p0],  cf[3][p1],  y1v);  // (1,0,1)
        triple_acc<3,3,1>(cg4,  a1, c1, cf[4][p0],  cf[4][p1],  y0v);  // (1,1,0)
        triple_acc<3,3,3>(cg5,  a1, c1, cf[5][p0],  cf[5][p1],  y1v);  // (1,1,1)
        triple_acc<3,3,5>(cg6,  a1, c1, cf[6][p0],  cf[6][p1],  y2v);  // (1,1,2)
        triple_acc<3,5,3>(cg7,  a1, c2, cf[7][p0],  cf[7][p1],  y1v);  // (1,2,1)
        triple_acc<3,5,5>(cg8,  a1, c2, cf[8][p0],  cf[8][p1],  y2v);  // (1,2,2)
        triple_acc<5,1,5>(cg9,  a2, c0, cf[9][p0],  cf[9][p1],  y2v);  // (2,0,2)
        triple_acc<5,3,3>(cg10, a2, c1, cf[10][p0], cf[10][p1], y1v);  // (2,1,1)
        triple_acc<5,3,5>(cg11, a2, c1, cf[11][p0], cf[11][p1], y2v);  // (2,1,2)
        triple_acc<5,5,1>(cg12, a2, c2, cf[12][p0], cf[12][p1], y0v);  // (2,2,0)
        triple_acc<5,5,3>(cg13, a2, c2, cf[13][p0], cf[13][p1], y1v);  // (2,2,1)
        triple_acc<5,5,5>(cg14, a2, c2, cf[14][p0], cf[14][p1], y2v);  // (2,2,2)

#pragma unroll
        for (int nn = 0; nn < 2; ++nn) {
            const int n = nb + nn;
            out[n * 128 + f] = y0v[0][nn];
#pragma unroll
            for (int k = 0; k < 3; ++k)
                out[Y1OFF + (n * 3 + k) * 128 + f] = y1v[k][nn];
#pragma unroll
            for (int k = 0; k < 5; ++k)
                out[Y2OFF + (n * 5 + k) * 128 + f] = y2v[k][nn];
        }
    }
}

extern "C" void kernel_launch(void* const* d_in, const int* in_sizes, int n_in,
                              void* d_out, int out_size, void* d_ws, size_t ws_size,
                              hipStream_t stream) {
    const float* x1_0 = (const float*)d_in[0];
    const float* x1_1 = (const float*)d_in[1];
    const float* x1_2 = (const float*)d_in[2];
    const float* x2_0 = (const float*)d_in[3];
    const float* x2_1 = (const float*)d_in[4];
    const float* x2_2 = (const float*)d_in[5];
    const float* rbf  = (const float*)d_in[6];
    // setup_inputs order: per triple, cg then W, interleaved
    const float* cg[15];
    const float* W[15];
    for (int t = 0; t < 15; ++t) {
        cg[t] = (const float*)d_in[7 + 2 * t];
        W[t]  = (const float*)d_in[8 + 2 * t];
    }
    float* out = (float*)d_out;

    const bool use_wt = (d_ws != nullptr) && (ws_size >= (size_t)WT_BYTES);

    dim3 grid(NPAIR / NB);   // 7500
    dim3 block(256);

    if (use_wt) {
        WPtrs P;
        for (int t = 0; t < 15; ++t) P.w[t] = W[t];
        transpose_W_kernel<<<dim3(4, 15), dim3(256), 0, stream>>>(P, (float*)d_ws);
        pair_mixing_kernel<true><<<grid, block, 0, stream>>>(
            x1_0, x1_1, x1_2, x2_0, x2_1, x2_2, rbf,
            cg[0], cg[1], cg[2], cg[3], cg[4], cg[5], cg[6], cg[7],
            cg[8], cg[9], cg[10], cg[11], cg[12], cg[13], cg[14],
            W[0], W[1], W[2], W[3], W[4], W[5], W[6], W[7],
            W[8], W[9], W[10], W[11], W[12], W[13], W[14],
            (const float*)d_ws, out);
    } else {
        pair_mixing_kernel<false><<<grid, block, 0, stream>>>(
            x1_0, x1_1, x1_2, x2_0, x2_1, x2_2, rbf,
            cg[0], cg[1], cg[2], cg[3], cg[4], cg[5], cg[6], cg[7],
            cg[8], cg[9], cg[10], cg[11], cg[12], cg[13], cg[14],
            W[0], W[1], W[2], W[3], W[4], W[5], W[6], W[7],
            W[8], W[9], W[10], W[11], W[12], W[13], W[14],
            nullptr, out);
    }
}